// Round 1
// baseline (255.517 us; speedup 1.0000x reference)
//
#include <hip/hip_runtime.h>
#include <hip/hip_bf16.h>

typedef __bf16 bf16_t;
typedef __bf16 bf16x4 __attribute__((ext_vector_type(4)));
typedef __bf16 bf16x8 __attribute__((ext_vector_type(8)));
typedef float f32x4 __attribute__((ext_vector_type(4)));

#define B_   2
#define L_   4096
#define DIM_ 1024
#define M_   (B_ * L_)          // 8192 total rows
#define MT_  (L_ / 128)         // 32 m-tiles per batch
#define NTASK_ ((MT_ * (MT_ + 1)) / 2)   // 528 lower-tri tiles per batch

// ---- async global->LDS, 16B per lane (wave-uniform LDS base + lane*16) ----
__device__ __forceinline__ void ld_g2l_16(const bf16_t* g, bf16_t* l) {
  __builtin_amdgcn_global_load_lds(
      (__attribute__((address_space(1))) void*)g,
      (__attribute__((address_space(3))) void*)l, 16, 0, 0);
}

// ---- fp32 -> bf16 convert (RNE, matches jnp astype) ----
__global__ void cvt_f32_bf16(const float* __restrict__ src,
                             bf16_t* __restrict__ dst, int n4) {
  int i = blockIdx.x * blockDim.x + threadIdx.x;
  if (i < n4) {
    float4 v = ((const float4*)src)[i];
    bf16x4 o = { (bf16_t)v.x, (bf16_t)v.y, (bf16_t)v.z, (bf16_t)v.w };
    ((bf16x4*)dst)[i] = o;
  }
}

// ---- shared 128x128 bt-GEMM core: acc[m,n] += sum_k A[m,k]*B[n,k], K-loop ----
// A,B pre-offset to tile start, K-contiguous rows. LDS tiles 128x32 linear.
__device__ __forceinline__ void mfma_bt_core(const bf16_t* __restrict__ A,
                                             const bf16_t* __restrict__ B,
                                             int K, bf16_t* As, bf16_t* Bs,
                                             f32x4 (&acc)[4][4]) {
  const int tid  = threadIdx.x;
  const int wave = tid >> 6, lane = tid & 63;
  const int quad = lane >> 4, l16 = lane & 15;
  const int wm = (wave >> 1) * 64, wn = (wave & 1) * 64;
  const int srow = lane >> 2;          // 0..15 within 16-row segment
  const int scol = (lane & 3) * 8;     // 0,8,16,24

  for (int kk = 0; kk < K; kk += 32) {
    __syncthreads();   // protect LDS from overwrite while prior reads in flight
#pragma unroll
    for (int c = 0; c < 2; ++c) {
      int seg = c * 4 + wave;          // 8 segments of 16 rows x 32 cols
      int row = seg * 16 + srow;
      ld_g2l_16(A + (size_t)row * K + kk + scol, As + seg * 512);
      ld_g2l_16(B + (size_t)row * K + kk + scol, Bs + seg * 512);
    }
    __syncthreads();   // compiler emits vmcnt(0) drain before s_barrier

    bf16x8 af[4], bfr[4];
#pragma unroll
    for (int i = 0; i < 4; ++i) {
      af[i]  = *(const bf16x8*)(As + (wm + i * 16 + l16) * 32 + quad * 8);
      bfr[i] = *(const bf16x8*)(Bs + (wn + i * 16 + l16) * 32 + quad * 8);
    }
#pragma unroll
    for (int i = 0; i < 4; ++i)
#pragma unroll
      for (int j = 0; j < 4; ++j)
        acc[i][j] = __builtin_amdgcn_mfma_f32_16x16x32_bf16(af[i], bfr[j],
                                                            acc[i][j], 0, 0, 0);
  }
}

// ---- projection GEMM: C = A @ W^T  (W stored [n,k] row-major == bt layout) ----
__global__ __launch_bounds__(256)
void proj_gemm(const bf16_t* __restrict__ A, const bf16_t* __restrict__ Wqb,
               const bf16_t* __restrict__ Wkb, bf16_t* __restrict__ Cq,
               bf16_t* __restrict__ Ck) {
  const int K = DIM_, N = DIM_;
  const bf16_t* Bm = (blockIdx.z == 0) ? Wqb : Wkb;
  bf16_t* Cm = (blockIdx.z == 0) ? Cq : Ck;
  __shared__ __attribute__((aligned(16))) bf16_t As[128 * 32];
  __shared__ __attribute__((aligned(16))) bf16_t Bs[128 * 32];
  const int tid = threadIdx.x;
  const int wave = tid >> 6, lane = tid & 63;
  const int quad = lane >> 4, l16 = lane & 15;
  const int wm = (wave >> 1) * 64, wn = (wave & 1) * 64;
  const int m0 = blockIdx.y * 128, n0 = blockIdx.x * 128;

  f32x4 acc[4][4] = {};
  mfma_bt_core(A + (size_t)m0 * K, Bm + (size_t)n0 * K, K, As, Bs, acc);

#pragma unroll
  for (int i = 0; i < 4; ++i)
#pragma unroll
    for (int j = 0; j < 4; ++j)
#pragma unroll
      for (int r = 0; r < 4; ++r) {
        int m = m0 + wm + i * 16 + quad * 4 + r;   // C/D: row=quad*4+reg
        int n = n0 + wn + j * 16 + l16;            //      col=lane&15
        Cm[(size_t)m * N + n] = (bf16_t)acc[i][j][r];
      }
}

// ---- RoPE in-place, bf16, pairs (j, j+512); pos = row % 4096 ----
__global__ void rope_kernel(bf16_t* __restrict__ x) {
  int row = blockIdx.x * 2 + (threadIdx.x >> 7);
  int j0  = (threadIdx.x & 127) * 4;
  int pos = row & (L_ - 1);
  bf16_t* p = x + (size_t)row * DIM_;
  bf16x4 v1 = *(const bf16x4*)(p + j0);
  bf16x4 v2 = *(const bf16x4*)(p + j0 + 512);
  bf16x4 o1, o2;
#pragma unroll
  for (int u = 0; u < 4; ++u) {
    int j = j0 + u;
    // inv_freq = 32^(-2j/1024) = 2^(-5j/512)
    float ang = (float)pos * exp2f((float)j * (-5.0f / 512.0f));
    float c = cosf(ang), s = sinf(ang);
    float cb = (float)(bf16_t)c, sb = (float)(bf16_t)s;  // ref rounds cos/sin to bf16
    float x1 = (float)v1[u], x2 = (float)v2[u];
    o1[u] = (bf16_t)(x1 * cb - x2 * sb);
    o2[u] = (bf16_t)(x2 * cb + x1 * sb);
  }
  *(bf16x4*)(p + j0) = o1;
  *(bf16x4*)(p + j0 + 512) = o2;
}

__global__ void zero_f32(float* p, int n) {
  int i = blockIdx.x * blockDim.x + threadIdx.x;
  if (i < n) p[i] = 0.0f;
}

// ---- causal exp-rowsum: o[b,m] = sum_{n<=m} exp(q_m . k_n / 32) ----
// grid.x = 2 * 528 equal-cost 128x128 tile tasks (triangular decode)
__global__ __launch_bounds__(256)
void attn_rowsum(const bf16_t* __restrict__ Q, const bf16_t* __restrict__ Kc,
                 float* __restrict__ o) {
  int t = blockIdx.x;
  int b = t / NTASK_;
  t -= b * NTASK_;
  int mt = (int)((sqrtf(8.0f * (float)t + 1.0f) - 1.0f) * 0.5f);
  while ((mt + 1) * (mt + 2) / 2 <= t) ++mt;
  while (mt * (mt + 1) / 2 > t) --mt;
  int nt = t - mt * (mt + 1) / 2;

  __shared__ __attribute__((aligned(16))) bf16_t As[128 * 32];
  __shared__ __attribute__((aligned(16))) bf16_t Bs[128 * 32];
  const int tid = threadIdx.x;
  const int wave = tid >> 6, lane = tid & 63;
  const int quad = lane >> 4, l16 = lane & 15;
  const int wm = (wave >> 1) * 64, wn = (wave & 1) * 64;

  const bf16_t* A  = Q  + (size_t)b * L_ * DIM_ + (size_t)mt * 128 * DIM_;
  const bf16_t* Bp = Kc + (size_t)b * L_ * DIM_ + (size_t)nt * 128 * DIM_;

  f32x4 acc[4][4] = {};
  mfma_bt_core(A, Bp, DIM_, As, Bs, acc);

  const bool diag = (mt == nt);
#pragma unroll
  for (int i = 0; i < 4; ++i) {
#pragma unroll
    for (int r = 0; r < 4; ++r) {
      int mrow = wm + i * 16 + quad * 4 + r;   // 0..127 in tile
      float sum = 0.0f;
#pragma unroll
      for (int j = 0; j < 4; ++j) {
        int ncol = wn + j * 16 + l16;
        float e = __expf(acc[i][j][r] * 0.03125f);   // /sqrt(1024)
        if (!diag || ncol <= mrow) sum += e;
      }
      // reduce across the 16 lanes holding distinct cols (masks<16 stay in quad)
      sum += __shfl_xor(sum, 1);
      sum += __shfl_xor(sum, 2);
      sum += __shfl_xor(sum, 4);
      sum += __shfl_xor(sum, 8);
      if (l16 == 0)
        atomicAdd(&o[b * L_ + mt * 128 + mrow], sum);
    }
  }
}

// ---- tiny MLP epilogue: out[row,d] = sum_i fc2_w[d,i]*relu(fc1_w[i]*o+fc1_b[i]) + fc2_b[d]
__global__ __launch_bounds__(256)
void mlp_out_kernel(const float* __restrict__ o, const float* __restrict__ fc1_w,
                    const float* __restrict__ fc1_b, const float* __restrict__ fc2_w,
                    const float* __restrict__ fc2_b, float* __restrict__ out) {
  const int R = 16;
  int row0 = blockIdx.x * R;
  int tid = threadIdx.x;
  __shared__ float h[R][16];
  {
    int rl = tid >> 4, i = tid & 15;
    float s = o[row0 + rl];
    h[rl][i] = fmaxf(fc1_w[i] * s + fc1_b[i], 0.0f);
  }
  __syncthreads();
  int d = tid * 4;
  float w[4][16];
#pragma unroll
  for (int c = 0; c < 4; ++c)
#pragma unroll
    for (int i = 0; i < 16; ++i) w[c][i] = fc2_w[(d + c) * 16 + i];
  float4 bb = *(const float4*)(fc2_b + d);
  for (int rl = 0; rl < R; ++rl) {
    float4 v = bb;
#pragma unroll
    for (int i = 0; i < 16; ++i) {
      float hv = h[rl][i];
      v.x += w[0][i] * hv; v.y += w[1][i] * hv;
      v.z += w[2][i] * hv; v.w += w[3][i] * hv;
    }
    *(float4*)(out + (size_t)(row0 + rl) * DIM_ + d) = v;
  }
}

extern "C" void kernel_launch(void* const* d_in, const int* in_sizes, int n_in,
                              void* d_out, int out_size, void* d_ws, size_t ws_size,
                              hipStream_t stream) {
  const float* hs    = (const float*)d_in[0];
  const float* Wq    = (const float*)d_in[1];
  const float* Wk    = (const float*)d_in[2];
  const float* fc1_w = (const float*)d_in[3];
  const float* fc1_b = (const float*)d_in[4];
  const float* fc2_w = (const float*)d_in[5];
  const float* fc2_b = (const float*)d_in[6];
  float* out = (float*)d_out;

  char* ws = (char*)d_ws;
  bf16_t* hs_bf = (bf16_t*)ws; ws += (size_t)M_ * DIM_ * 2;
  bf16_t* wq_bf = (bf16_t*)ws; ws += (size_t)DIM_ * DIM_ * 2;
  bf16_t* wk_bf = (bf16_t*)ws; ws += (size_t)DIM_ * DIM_ * 2;
  bf16_t* q_bf  = (bf16_t*)ws; ws += (size_t)M_ * DIM_ * 2;
  bf16_t* k_bf  = (bf16_t*)ws; ws += (size_t)M_ * DIM_ * 2;
  float*  o     = (float*)ws;  // M_ floats

  cvt_f32_bf16<<<M_ * DIM_ / 4 / 256, 256, 0, stream>>>(hs, hs_bf, M_ * DIM_ / 4);
  cvt_f32_bf16<<<DIM_ * DIM_ / 4 / 256, 256, 0, stream>>>(Wq, wq_bf, DIM_ * DIM_ / 4);
  cvt_f32_bf16<<<DIM_ * DIM_ / 4 / 256, 256, 0, stream>>>(Wk, wk_bf, DIM_ * DIM_ / 4);

  dim3 gg(DIM_ / 128, M_ / 128, 2);
  proj_gemm<<<gg, 256, 0, stream>>>(hs_bf, wq_bf, wk_bf, q_bf, k_bf);

  rope_kernel<<<M_ / 2, 256, 0, stream>>>(q_bf);
  rope_kernel<<<M_ / 2, 256, 0, stream>>>(k_bf);

  zero_f32<<<M_ / 256, 256, 0, stream>>>(o, M_);
  attn_rowsum<<<B_ * NTASK_, 256, 0, stream>>>(q_bf, k_bf, o);

  mlp_out_kernel<<<M_ / 16, 256, 0, stream>>>(o, fc1_w, fc1_b, fc2_w, fc2_b, out);
}

// Round 2
// 244.998 us; speedup vs baseline: 1.0429x; 1.0429x over previous
//
#include <hip/hip_runtime.h>
#include <hip/hip_bf16.h>

typedef __bf16 bf16_t;
typedef __bf16 bf16x4 __attribute__((ext_vector_type(4)));
typedef __bf16 bf16x8 __attribute__((ext_vector_type(8)));
typedef float f32x4 __attribute__((ext_vector_type(4)));

#define B_   2
#define L_   4096
#define DIM_ 1024
#define M_   (B_ * L_)          // 8192 total rows
// attn: 256-row m-tiles (16/batch), 128-col n-tiles; tasks/batch = 16^2+16 = 272
#define NTASK2_ 272

// ---- async global->LDS, 16B per lane (wave-uniform LDS base + lane*16) ----
__device__ __forceinline__ void ld_g2l_16(const bf16_t* g, bf16_t* l) {
  __builtin_amdgcn_global_load_lds(
      (__attribute__((address_space(1))) void*)g,
      (__attribute__((address_space(3))) void*)l, 16, 0, 0);
}

// ---- fused fp32 -> bf16 convert for hs, Wq, Wk (RNE, matches jnp astype) ----
__global__ void cvt_all(const float* __restrict__ hs, const float* __restrict__ wq,
                        const float* __restrict__ wk, bf16_t* __restrict__ hs_b,
                        bf16_t* __restrict__ wq_b, bf16_t* __restrict__ wk_b) {
  const int N_HS = M_ * DIM_ / 4, N_W = DIM_ * DIM_ / 4;
  int i = blockIdx.x * blockDim.x + threadIdx.x;
  const float* s; bf16_t* d; int idx;
  if (i < N_HS)            { s = hs; d = hs_b; idx = i; }
  else if (i < N_HS + N_W) { s = wq; d = wq_b; idx = i - N_HS; }
  else                     { s = wk; d = wk_b; idx = i - N_HS - N_W; }
  float4 v = ((const float4*)s)[idx];
  bf16x4 o = { (bf16_t)v.x, (bf16_t)v.y, (bf16_t)v.z, (bf16_t)v.w };
  ((bf16x4*)d)[idx] = o;
}

// ---- shared 256x128 bt-GEMM core: acc[m,n] += sum_k A[m,k]*B[n,k] ----
// A: 256 rows, B: 128 rows, both K-contiguous. Wave w owns rows [w*64,w*64+64),
// all 128 cols -> acc[4][8]. 128 MFMA / barrier-pair (2x m97 density).
__device__ __forceinline__ void core_256x128(const bf16_t* __restrict__ A,
                                             const bf16_t* __restrict__ B,
                                             int K, bf16_t* As, bf16_t* Bs,
                                             f32x4 (&acc)[4][8]) {
  const int tid  = threadIdx.x;
  const int wave = tid >> 6, lane = tid & 63;
  const int quad = lane >> 4, l16 = lane & 15;
  const int srow = lane >> 2;          // 0..15 within a 16-row segment
  const int scol = (lane & 3) * 8;     // 0,8,16,24

  for (int kk = 0; kk < K; kk += 32) {
    __syncthreads();   // prior ds_reads done before LDS overwrite
#pragma unroll
    for (int c = 0; c < 6; ++c) {
      int seg = c * 4 + wave;          // 24 segs: 16 for A (256x32), 8 for B (128x32)
      if (seg < 16) {
        int row = seg * 16 + srow;
        ld_g2l_16(A + (size_t)row * K + kk + scol, As + seg * 512);
      } else {
        int row = (seg - 16) * 16 + srow;
        ld_g2l_16(B + (size_t)row * K + kk + scol, Bs + (seg - 16) * 512);
      }
    }
    __syncthreads();   // vmcnt(0) drain emitted here

    bf16x8 af[4], bfr[8];
#pragma unroll
    for (int i = 0; i < 4; ++i)
      af[i] = *(const bf16x8*)(As + (wave * 64 + i * 16 + l16) * 32 + quad * 8);
#pragma unroll
    for (int j = 0; j < 8; ++j)
      bfr[j] = *(const bf16x8*)(Bs + (j * 16 + l16) * 32 + quad * 8);
#pragma unroll
    for (int i = 0; i < 4; ++i)
#pragma unroll
      for (int j = 0; j < 8; ++j)
        acc[i][j] = __builtin_amdgcn_mfma_f32_16x16x32_bf16(af[i], bfr[j],
                                                            acc[i][j], 0, 0, 0);
  }
}

// ---- projection GEMM: C = A @ W^T, 256x128 C-tiles ----
__global__ __launch_bounds__(256, 2)
void proj_gemm(const bf16_t* __restrict__ A, const bf16_t* __restrict__ Wqb,
               const bf16_t* __restrict__ Wkb, bf16_t* __restrict__ Cq,
               bf16_t* __restrict__ Ck) {
  const int K = DIM_, N = DIM_;
  const bf16_t* Bm = (blockIdx.z == 0) ? Wqb : Wkb;
  bf16_t* Cm = (blockIdx.z == 0) ? Cq : Ck;
  __shared__ __attribute__((aligned(16))) bf16_t As[256 * 32];
  __shared__ __attribute__((aligned(16))) bf16_t Bs[128 * 32];
  const int tid = threadIdx.x;
  const int wave = tid >> 6, lane = tid & 63;
  const int quad = lane >> 4, l16 = lane & 15;
  const int m0 = blockIdx.y * 256, n0 = blockIdx.x * 128;

  f32x4 acc[4][8] = {};
  core_256x128(A + (size_t)m0 * K, Bm + (size_t)n0 * K, K, As, Bs, acc);

#pragma unroll
  for (int i = 0; i < 4; ++i)
#pragma unroll
    for (int j = 0; j < 8; ++j)
#pragma unroll
      for (int r = 0; r < 4; ++r) {
        int m = m0 + wave * 64 + i * 16 + quad * 4 + r;  // C/D: row=quad*4+reg
        int n = n0 + j * 16 + l16;                       //      col=lane&15
        Cm[(size_t)m * N + n] = (bf16_t)acc[i][j][r];
      }
}

// ---- RoPE in-place, bf16, pairs (j, j+512); blockIdx.y picks q/k ----
__global__ void rope_kernel(bf16_t* __restrict__ q, bf16_t* __restrict__ k) {
  bf16_t* x = blockIdx.y ? k : q;
  int row = blockIdx.x * 2 + (threadIdx.x >> 7);
  int j0  = (threadIdx.x & 127) * 4;
  int pos = row & (L_ - 1);
  bf16_t* p = x + (size_t)row * DIM_;
  bf16x4 v1 = *(const bf16x4*)(p + j0);
  bf16x4 v2 = *(const bf16x4*)(p + j0 + 512);
  bf16x4 o1, o2;
#pragma unroll
  for (int u = 0; u < 4; ++u) {
    int j = j0 + u;
    // inv_freq = 32^(-2j/1024) = 2^(-5j/512)
    float ang = (float)pos * exp2f((float)j * (-5.0f / 512.0f));
    float c = cosf(ang), s = sinf(ang);
    float cb = (float)(bf16_t)c, sb = (float)(bf16_t)s;  // ref rounds cos/sin to bf16
    float x1 = (float)v1[u], x2 = (float)v2[u];
    o1[u] = (bf16_t)(x1 * cb - x2 * sb);
    o2[u] = (bf16_t)(x2 * cb + x1 * sb);
  }
  *(bf16x4*)(p + j0) = o1;
  *(bf16x4*)(p + j0 + 512) = o2;
}

// ---- causal exp-rowsum: o[b,m] = sum_{n<=m} exp(q_m . k_n / 32) ----
// 256x128 tiles; per batch: mi in 0..15 needs nt in 0..2mi+1 -> 272 tasks
__global__ __launch_bounds__(256, 2)
void attn_rowsum(const bf16_t* __restrict__ Q, const bf16_t* __restrict__ Kc,
                 float* __restrict__ o) {
  int t = blockIdx.x;
  int b = t / NTASK2_;
  t -= b * NTASK2_;
  int mi = (int)((sqrtf(4.0f * (float)t + 1.0f) - 1.0f) * 0.5f);
  while ((mi + 1) * (mi + 2) <= t) ++mi;     // (mi+1)^2+(mi+1) <= t
  while (mi * (mi + 1) > t) --mi;            // mi^2+mi > t
  int nt = t - mi * (mi + 1);

  __shared__ __attribute__((aligned(16))) bf16_t As[256 * 32];
  __shared__ __attribute__((aligned(16))) bf16_t Bs[128 * 32];
  const int tid = threadIdx.x;
  const int wave = tid >> 6, lane = tid & 63;
  const int quad = lane >> 4, l16 = lane & 15;

  const bf16_t* A  = Q  + (size_t)b * L_ * DIM_ + (size_t)mi * 256 * DIM_;
  const bf16_t* Bp = Kc + (size_t)b * L_ * DIM_ + (size_t)nt * 128 * DIM_;

  f32x4 acc[4][8] = {};
  core_256x128(A, Bp, DIM_, As, Bs, acc);

  const bool masked = (nt >= 2 * mi);   // tile touches the diagonal
#pragma unroll
  for (int i = 0; i < 4; ++i) {
#pragma unroll
    for (int r = 0; r < 4; ++r) {
      int grow = mi * 256 + wave * 64 + i * 16 + quad * 4 + r;  // row in batch
      float sum = 0.0f;
#pragma unroll
      for (int j = 0; j < 8; ++j) {
        int gcol = nt * 128 + j * 16 + l16;
        float e = __expf(acc[i][j][r] * 0.03125f);   // /sqrt(1024)
        if (!masked || gcol <= grow) sum += e;
      }
      sum += __shfl_xor(sum, 1);
      sum += __shfl_xor(sum, 2);
      sum += __shfl_xor(sum, 4);
      sum += __shfl_xor(sum, 8);
      if (l16 == 0)
        atomicAdd(&o[b * L_ + grow], sum);
    }
  }
}

// ---- tiny MLP epilogue ----
__global__ __launch_bounds__(256)
void mlp_out_kernel(const float* __restrict__ o, const float* __restrict__ fc1_w,
                    const float* __restrict__ fc1_b, const float* __restrict__ fc2_w,
                    const float* __restrict__ fc2_b, float* __restrict__ out) {
  const int R = 16;
  int row0 = blockIdx.x * R;
  int tid = threadIdx.x;
  __shared__ float h[R][16];
  {
    int rl = tid >> 4, i = tid & 15;
    float s = o[row0 + rl];
    h[rl][i] = fmaxf(fc1_w[i] * s + fc1_b[i], 0.0f);
  }
  __syncthreads();
  int d = tid * 4;
  float w[4][16];
#pragma unroll
  for (int c = 0; c < 4; ++c)
#pragma unroll
    for (int i = 0; i < 16; ++i) w[c][i] = fc2_w[(d + c) * 16 + i];
  float4 bb = *(const float4*)(fc2_b + d);
  for (int rl = 0; rl < R; ++rl) {
    float4 v = bb;
#pragma unroll
    for (int i = 0; i < 16; ++i) {
      float hv = h[rl][i];
      v.x += w[0][i] * hv; v.y += w[1][i] * hv;
      v.z += w[2][i] * hv; v.w += w[3][i] * hv;
    }
    *(float4*)(out + (size_t)(row0 + rl) * DIM_ + d) = v;
  }
}

extern "C" void kernel_launch(void* const* d_in, const int* in_sizes, int n_in,
                              void* d_out, int out_size, void* d_ws, size_t ws_size,
                              hipStream_t stream) {
  const float* hs    = (const float*)d_in[0];
  const float* Wq    = (const float*)d_in[1];
  const float* Wk    = (const float*)d_in[2];
  const float* fc1_w = (const float*)d_in[3];
  const float* fc1_b = (const float*)d_in[4];
  const float* fc2_w = (const float*)d_in[5];
  const float* fc2_b = (const float*)d_in[6];
  float* out = (float*)d_out;

  char* ws = (char*)d_ws;
  bf16_t* hs_bf = (bf16_t*)ws; ws += (size_t)M_ * DIM_ * 2;
  bf16_t* wq_bf = (bf16_t*)ws; ws += (size_t)DIM_ * DIM_ * 2;
  bf16_t* wk_bf = (bf16_t*)ws; ws += (size_t)DIM_ * DIM_ * 2;
  bf16_t* q_bf  = (bf16_t*)ws; ws += (size_t)M_ * DIM_ * 2;
  bf16_t* k_bf  = (bf16_t*)ws; ws += (size_t)M_ * DIM_ * 2;
  float*  o     = (float*)ws;  // M_ floats

  const int n4 = (M_ * DIM_ + 2 * DIM_ * DIM_) / 4;
  cvt_all<<<n4 / 256, 256, 0, stream>>>(hs, Wq, Wk, hs_bf, wq_bf, wk_bf);

  dim3 gg(DIM_ / 128, M_ / 256, 2);
  proj_gemm<<<gg, 256, 0, stream>>>(hs_bf, wq_bf, wk_bf, q_bf, k_bf);

  dim3 gr(M_ / 2, 2);
  rope_kernel<<<gr, 256, 0, stream>>>(q_bf, k_bf);

  hipMemsetAsync(o, 0, M_ * sizeof(float), stream);
  attn_rowsum<<<B_ * NTASK2_, 256, 0, stream>>>(q_bf, k_bf, o);

  mlp_out_kernel<<<M_ / 16, 256, 0, stream>>>(o, fc1_w, fc1_b, fc2_w, fc2_b, out);
}

// Round 3
// 244.303 us; speedup vs baseline: 1.0459x; 1.0028x over previous
//
#include <hip/hip_runtime.h>
#include <hip/hip_bf16.h>

typedef __bf16 bf16_t;
typedef __bf16 bf16x4 __attribute__((ext_vector_type(4)));
typedef __bf16 bf16x8 __attribute__((ext_vector_type(8)));
typedef float f32x4 __attribute__((ext_vector_type(4)));

#define B_   2
#define L_   4096
#define DIM_ 1024
#define M_   (B_ * L_)          // 8192 total rows
// attn: 256-row m-tiles (16/batch), 128-col n-tiles; tasks/batch = 16^2+16 = 272
#define NTASK2_ 272

// ---- async global->LDS, 16B per lane (wave-uniform LDS base + lane*16) ----
__device__ __forceinline__ void ld_g2l_16(const bf16_t* g, bf16_t* l) {
  __builtin_amdgcn_global_load_lds(
      (__attribute__((address_space(1))) void*)g,
      (__attribute__((address_space(3))) void*)l, 16, 0, 0);
}

// ---- fused fp32 -> bf16 convert for hs, Wq, Wk (RNE, matches jnp astype) ----
__global__ void cvt_all(const float* __restrict__ hs, const float* __restrict__ wq,
                        const float* __restrict__ wk, bf16_t* __restrict__ hs_b,
                        bf16_t* __restrict__ wq_b, bf16_t* __restrict__ wk_b) {
  const int N_HS = M_ * DIM_ / 4, N_W = DIM_ * DIM_ / 4;
  int i = blockIdx.x * blockDim.x + threadIdx.x;
  const float* s; bf16_t* d; int idx;
  if (i < N_HS)            { s = hs; d = hs_b; idx = i; }
  else if (i < N_HS + N_W) { s = wq; d = wq_b; idx = i - N_HS; }
  else                     { s = wk; d = wk_b; idx = i - N_HS - N_W; }
  float4 v = ((const float4*)s)[idx];
  bf16x4 o = { (bf16_t)v.x, (bf16_t)v.y, (bf16_t)v.z, (bf16_t)v.w };
  ((bf16x4*)d)[idx] = o;
}

// ---- shared 256x128 bt-GEMM core: acc[m,n] += sum_k A[m,k]*B[n,k] ----
// LDS layout: 16-row x 32-col segments (1024B), XOR-swizzled: 16B chunk c of
// row r lives at slot c ^ ((r>>1)&3). Staging lanes fetch the permuted global
// chunk so the fixed lane->lane*16 LDS write lands it swizzled; ds_read_b128
// then hits each bank exactly 2x per quad (2-way = free, m136).
__device__ __forceinline__ void core_256x128(const bf16_t* __restrict__ A,
                                             const bf16_t* __restrict__ B,
                                             int K, bf16_t* As, bf16_t* Bs,
                                             f32x4 (&acc)[4][8]) {
  const int tid  = threadIdx.x;
  const int wave = tid >> 6, lane = tid & 63;
  const int quad = lane >> 4, l16 = lane & 15;
  const int srow = lane >> 2;                                  // 0..15 in segment
  const int scol = (((lane & 3) ^ ((lane >> 3) & 3)) * 8);     // swizzled chunk
  const int rsw  = ((l16 >> 1) & 3) * 8;                       // read-side swizzle

  for (int kk = 0; kk < K; kk += 32) {
    __syncthreads();   // prior ds_reads done before LDS overwrite
#pragma unroll
    for (int c = 0; c < 6; ++c) {
      int seg = c * 4 + wave;          // 24 segs: 16 for A (256x32), 8 for B (128x32)
      if (seg < 16) {
        int row = seg * 16 + srow;
        ld_g2l_16(A + (size_t)row * K + kk + scol, As + seg * 512);
      } else {
        int row = (seg - 16) * 16 + srow;
        ld_g2l_16(B + (size_t)row * K + kk + scol, Bs + (seg - 16) * 512);
      }
    }
    __syncthreads();   // vmcnt(0) drain emitted here

    bf16x8 af[4], bfr[8];
#pragma unroll
    for (int i = 0; i < 4; ++i)
      af[i] = *(const bf16x8*)(As + (wave * 64 + i * 16 + l16) * 32 +
                               ((quad * 8) ^ rsw));
#pragma unroll
    for (int j = 0; j < 8; ++j)
      bfr[j] = *(const bf16x8*)(Bs + (j * 16 + l16) * 32 + ((quad * 8) ^ rsw));
#pragma unroll
    for (int i = 0; i < 4; ++i)
#pragma unroll
      for (int j = 0; j < 8; ++j)
        acc[i][j] = __builtin_amdgcn_mfma_f32_16x16x32_bf16(af[i], bfr[j],
                                                            acc[i][j], 0, 0, 0);
  }
}

// ---- projection GEMM: C = A @ W^T, 256x128 C-tiles ----
__global__ __launch_bounds__(256, 2)
void proj_gemm(const bf16_t* __restrict__ A, const bf16_t* __restrict__ Wqb,
               const bf16_t* __restrict__ Wkb, bf16_t* __restrict__ Cq,
               bf16_t* __restrict__ Ck) {
  const int K = DIM_, N = DIM_;
  const bf16_t* Bm = (blockIdx.z == 0) ? Wqb : Wkb;
  bf16_t* Cm = (blockIdx.z == 0) ? Cq : Ck;
  __shared__ __attribute__((aligned(16))) bf16_t As[256 * 32];
  __shared__ __attribute__((aligned(16))) bf16_t Bs[128 * 32];
  const int tid = threadIdx.x;
  const int wave = tid >> 6, lane = tid & 63;
  const int quad = lane >> 4, l16 = lane & 15;
  const int m0 = blockIdx.y * 256, n0 = blockIdx.x * 128;

  f32x4 acc[4][8] = {};
  core_256x128(A + (size_t)m0 * K, Bm + (size_t)n0 * K, K, As, Bs, acc);

#pragma unroll
  for (int i = 0; i < 4; ++i)
#pragma unroll
    for (int j = 0; j < 8; ++j)
#pragma unroll
      for (int r = 0; r < 4; ++r) {
        int m = m0 + wave * 64 + i * 16 + quad * 4 + r;  // C/D: row=quad*4+reg
        int n = n0 + j * 16 + l16;                       //      col=lane&15
        Cm[(size_t)m * N + n] = (bf16_t)acc[i][j][r];
      }
}

// ---- RoPE in-place, bf16, pairs (j, j+512); blockIdx.y picks q/k ----
__global__ void rope_kernel(bf16_t* __restrict__ q, bf16_t* __restrict__ k) {
  bf16_t* x = blockIdx.y ? k : q;
  int row = blockIdx.x * 2 + (threadIdx.x >> 7);
  int j0  = (threadIdx.x & 127) * 4;
  int pos = row & (L_ - 1);
  bf16_t* p = x + (size_t)row * DIM_;
  bf16x4 v1 = *(const bf16x4*)(p + j0);
  bf16x4 v2 = *(const bf16x4*)(p + j0 + 512);
  bf16x4 o1, o2;
#pragma unroll
  for (int u = 0; u < 4; ++u) {
    int j = j0 + u;
    // inv_freq = 32^(-2j/1024) = 2^(-5j/512)
    float ang = (float)pos * exp2f((float)j * (-5.0f / 512.0f));
    float c = cosf(ang), s = sinf(ang);
    float cb = (float)(bf16_t)c, sb = (float)(bf16_t)s;  // ref rounds cos/sin to bf16
    float x1 = (float)v1[u], x2 = (float)v2[u];
    o1[u] = (bf16_t)(x1 * cb - x2 * sb);
    o2[u] = (bf16_t)(x2 * cb + x1 * sb);
  }
  *(bf16x4*)(p + j0) = o1;
  *(bf16x4*)(p + j0 + 512) = o2;
}

// ---- causal exp-rowsum: o[b,m] = sum_{n<=m} exp(q_m . k_n / 32) ----
// 256x128 tiles; per batch: mi in 0..15 needs nt in 0..2mi+1 -> 272 tasks
__global__ __launch_bounds__(256, 2)
void attn_rowsum(const bf16_t* __restrict__ Q, const bf16_t* __restrict__ Kc,
                 float* __restrict__ o) {
  int t = blockIdx.x;
  int b = t / NTASK2_;
  t -= b * NTASK2_;
  int mi = (int)((sqrtf(4.0f * (float)t + 1.0f) - 1.0f) * 0.5f);
  while ((mi + 1) * (mi + 2) <= t) ++mi;     // (mi+1)^2+(mi+1) <= t
  while (mi * (mi + 1) > t) --mi;            // mi^2+mi > t
  int nt = t - mi * (mi + 1);

  __shared__ __attribute__((aligned(16))) bf16_t As[256 * 32];
  __shared__ __attribute__((aligned(16))) bf16_t Bs[128 * 32];
  const int tid = threadIdx.x;
  const int wave = tid >> 6, lane = tid & 63;
  const int quad = lane >> 4, l16 = lane & 15;

  const bf16_t* A  = Q  + (size_t)b * L_ * DIM_ + (size_t)mi * 256 * DIM_;
  const bf16_t* Bp = Kc + (size_t)b * L_ * DIM_ + (size_t)nt * 128 * DIM_;

  f32x4 acc[4][8] = {};
  core_256x128(A, Bp, DIM_, As, Bs, acc);

  const bool masked = (nt >= 2 * mi);   // tile touches the diagonal
#pragma unroll
  for (int i = 0; i < 4; ++i) {
#pragma unroll
    for (int r = 0; r < 4; ++r) {
      int grow = mi * 256 + wave * 64 + i * 16 + quad * 4 + r;  // row in batch
      float sum = 0.0f;
#pragma unroll
      for (int j = 0; j < 8; ++j) {
        int gcol = nt * 128 + j * 16 + l16;
        float e = __expf(acc[i][j][r] * 0.03125f);   // /sqrt(1024)
        if (!masked || gcol <= grow) sum += e;
      }
      sum += __shfl_xor(sum, 1);
      sum += __shfl_xor(sum, 2);
      sum += __shfl_xor(sum, 4);
      sum += __shfl_xor(sum, 8);
      if (l16 == 0)
        atomicAdd(&o[b * L_ + grow], sum);
    }
  }
}

// ---- tiny MLP epilogue ----
__global__ __launch_bounds__(256)
void mlp_out_kernel(const float* __restrict__ o, const float* __restrict__ fc1_w,
                    const float* __restrict__ fc1_b, const float* __restrict__ fc2_w,
                    const float* __restrict__ fc2_b, float* __restrict__ out) {
  const int R = 16;
  int row0 = blockIdx.x * R;
  int tid = threadIdx.x;
  __shared__ float h[R][16];
  {
    int rl = tid >> 4, i = tid & 15;
    float s = o[row0 + rl];
    h[rl][i] = fmaxf(fc1_w[i] * s + fc1_b[i], 0.0f);
  }
  __syncthreads();
  int d = tid * 4;
  float w[4][16];
#pragma unroll
  for (int c = 0; c < 4; ++c)
#pragma unroll
    for (int i = 0; i < 16; ++i) w[c][i] = fc2_w[(d + c) * 16 + i];
  float4 bb = *(const float4*)(fc2_b + d);
  for (int rl = 0; rl < R; ++rl) {
    float4 v = bb;
#pragma unroll
    for (int i = 0; i < 16; ++i) {
      float hv = h[rl][i];
      v.x += w[0][i] * hv; v.y += w[1][i] * hv;
      v.z += w[2][i] * hv; v.w += w[3][i] * hv;
    }
    *(float4*)(out + (size_t)(row0 + rl) * DIM_ + d) = v;
  }
}

extern "C" void kernel_launch(void* const* d_in, const int* in_sizes, int n_in,
                              void* d_out, int out_size, void* d_ws, size_t ws_size,
                              hipStream_t stream) {
  const float* hs    = (const float*)d_in[0];
  const float* Wq    = (const float*)d_in[1];
  const float* Wk    = (const float*)d_in[2];
  const float* fc1_w = (const float*)d_in[3];
  const float* fc1_b = (const float*)d_in[4];
  const float* fc2_w = (const float*)d_in[5];
  const float* fc2_b = (const float*)d_in[6];
  float* out = (float*)d_out;

  char* ws = (char*)d_ws;
  bf16_t* hs_bf = (bf16_t*)ws; ws += (size_t)M_ * DIM_ * 2;
  bf16_t* wq_bf = (bf16_t*)ws; ws += (size_t)DIM_ * DIM_ * 2;
  bf16_t* wk_bf = (bf16_t*)ws; ws += (size_t)DIM_ * DIM_ * 2;
  bf16_t* q_bf  = (bf16_t*)ws; ws += (size_t)M_ * DIM_ * 2;
  bf16_t* k_bf  = (bf16_t*)ws; ws += (size_t)M_ * DIM_ * 2;
  float*  o     = (float*)ws;  // M_ floats

  const int n4 = (M_ * DIM_ + 2 * DIM_ * DIM_) / 4;
  cvt_all<<<n4 / 256, 256, 0, stream>>>(hs, Wq, Wk, hs_bf, wq_bf, wk_bf);

  dim3 gg(DIM_ / 128, M_ / 256, 2);
  proj_gemm<<<gg, 256, 0, stream>>>(hs_bf, wq_bf, wk_bf, q_bf, k_bf);

  dim3 gr(M_ / 2, 2);
  rope_kernel<<<gr, 256, 0, stream>>>(q_bf, k_bf);

  hipMemsetAsync(o, 0, M_ * sizeof(float), stream);
  attn_rowsum<<<B_ * NTASK2_, 256, 0, stream>>>(q_bf, k_bf, o);

  mlp_out_kernel<<<M_ / 16, 256, 0, stream>>>(o, fc1_w, fc1_b, fc2_w, fc2_b, out);
}